// Round 11
// baseline (39.652 us; speedup 1.0000x reference)
//
#include <hip/hip_runtime.h>
#include <hip/hip_bf16.h>

#define BB   32
#define SS   1024
#define RR   1024
#define HID  512
#define OUTD 1024

// Layer 1 (proven round-9 form): one wave per (4-j tile, 4-batch tile).
// Grid: 128 j-quads * 8 b-quads = 1024 one-wave blocks.
__global__ __launch_bounds__(64) void layer1_kernel(
    const float* __restrict__ rep, const float* __restrict__ W1,
    const float* __restrict__ b1, float* __restrict__ h) {
  const int lane = threadIdx.x;
  const int g    = lane >> 4;
  const int l16  = lane & 15;
  const int jq   = blockIdx.x >> 3;        // 0..127
  const int b0   = (blockIdx.x & 7) << 2;  // 0,4,..,28
  const int j    = (jq << 2) + g;

  const float4* w4 = reinterpret_cast<const float4*>(W1 + (size_t)j * RR);
  const float4* r0 = reinterpret_cast<const float4*>(rep + (size_t)b0 * RR);
  const float4* r1 = reinterpret_cast<const float4*>(rep + (size_t)(b0 + 1) * RR);
  const float4* r2 = reinterpret_cast<const float4*>(rep + (size_t)(b0 + 2) * RR);
  const float4* r3 = reinterpret_cast<const float4*>(rep + (size_t)(b0 + 3) * RR);
  float a0 = 0.f, a1 = 0.f, a2 = 0.f, a3 = 0.f;
#pragma unroll
  for (int t = 0; t < 16; ++t) {           // 256 float4 / 16 lanes
    const int idx = l16 + 16 * t;
    const float4 w = w4[idx];
    const float4 x0 = r0[idx];
    const float4 x1 = r1[idx];
    const float4 x2 = r2[idx];
    const float4 x3 = r3[idx];
    a0 += w.x * x0.x + w.y * x0.y + w.z * x0.z + w.w * x0.w;
    a1 += w.x * x1.x + w.y * x1.y + w.z * x1.z + w.w * x1.w;
    a2 += w.x * x2.x + w.y * x2.y + w.z * x2.z + w.w * x2.w;
    a3 += w.x * x3.x + w.y * x3.y + w.z * x3.z + w.w * x3.w;
  }
#pragma unroll
  for (int m = 1; m <= 8; m <<= 1) {
    a0 += __shfl_xor(a0, m);
    a1 += __shfl_xor(a1, m);
    a2 += __shfl_xor(a2, m);
    a3 += __shfl_xor(a3, m);
  }
  if (l16 == 0) {
    const float bb = b1[j];
    h[(size_t)b0 * HID + j]       = fmaxf(a0 + bb, 0.f);
    h[(size_t)(b0 + 1) * HID + j] = fmaxf(a1 + bb, 0.f);
    h[(size_t)(b0 + 2) * HID + j] = fmaxf(a2 + bb, 0.f);
    h[(size_t)(b0 + 3) * HID + j] = fmaxf(a3 + bb, 0.f);
  }
}

// Fused layer2 + broadcast, max-occupancy variant.
// Block = 1024 threads (16 waves), (b, k-chunk of 256, s-chunk of 256).
// Grid = 32 * 4 * 4 = 512 blocks -> 2 blocks/CU = 32 waves/CU (FULL).
// Dot phase: 64 16-lane groups x 4 k's = 32 serial MACs/thread.
// Write phase: 256 rows x 1 KB contiguous chunks (16 stores/thread).
// No out[b,0,:] round-trip: every block computes its own k-slice.
__global__ __launch_bounds__(1024) void l2bcast_kernel(
    const float* __restrict__ h, const float* __restrict__ W2,
    const float* __restrict__ b2, float* __restrict__ out) {
  __shared__ float s_h[HID];      // 2 KB
  __shared__ float s_o[256];      // 1 KB
  const int tid = threadIdx.x;
  const int b   = blockIdx.x >> 4;         // 0..31
  const int kc  = (blockIdx.x >> 2) & 3;   // 0..3
  const int sc  = blockIdx.x & 3;          // 0..3
  const int k0  = kc << 8;

  // stage h[b,:] (512 floats)
  if (tid < 256)
    reinterpret_cast<float2*>(s_h)[tid] =
        reinterpret_cast<const float2*>(h + (size_t)b * HID)[tid];
  __syncthreads();

  const int gg  = tid >> 4;      // 0..63
  const int l16 = tid & 15;
  const float4* s_h4 = reinterpret_cast<const float4*>(s_h);
#pragma unroll
  for (int i = 0; i < 4; ++i) {
    const int k = k0 + (i << 6) + gg;
    const float4* w = reinterpret_cast<const float4*>(W2 + (size_t)k * HID);
    float acc = 0.f;
#pragma unroll
    for (int t = 0; t < 8; ++t) {          // 128 float4 / 16 lanes
      const float4 wv = w[l16 + 16 * t];
      const float4 xv = s_h4[l16 + 16 * t];
      acc += wv.x * xv.x + wv.y * xv.y + wv.z * xv.z + wv.w * xv.w;
    }
#pragma unroll
    for (int m = 1; m <= 8; m <<= 1) acc += __shfl_xor(acc, m);
    if (l16 == 0) s_o[(i << 6) + gg] = acc + b2[k];
  }
  __syncthreads();

  // write phase: rows sc*256 .. sc*256+255. 16 rows per pass, 16 passes;
  // each row gets a contiguous 1 KB chunk (64 lanes x float4).
  const int row = tid >> 6;                // 0..15
  const int col = tid & 63;                // float4 col within chunk
  const float4 v = reinterpret_cast<const float4*>(s_o)[col];
  float4* __restrict__ o4 =
      reinterpret_cast<float4*>(out) + (size_t)b * SS * (OUTD / 4) + (k0 >> 2);
  const int s0 = (sc << 8) + row;
#pragma unroll
  for (int p = 0; p < 16; ++p) {
    const int s = s0 + (p << 4);
    o4[(size_t)s * (OUTD / 4) + col] = v;
  }
}

extern "C" void kernel_launch(void* const* d_in, const int* in_sizes, int n_in,
                              void* d_out, int out_size, void* d_ws, size_t ws_size,
                              hipStream_t stream) {
  const float* rep = (const float*)d_in[0];
  // d_in[1] = size_matrix: only its shape matters (ones_like) -> unused
  const float* W1 = (const float*)d_in[2];
  const float* b1 = (const float*)d_in[3];
  const float* W2 = (const float*)d_in[4];
  const float* b2 = (const float*)d_in[5];
  float* out = (float*)d_out;
  float* h   = (float*)d_ws;               // 32*512 floats = 64 KB

  layer1_kernel<<<1024, 64, 0, stream>>>(rep, W1, b1, h);
  l2bcast_kernel<<<512, 1024, 0, stream>>>(h, W2, b2, out);
}

// Round 12
// 33.284 us; speedup vs baseline: 1.1913x; 1.1913x over previous
//
#include <hip/hip_runtime.h>
#include <hip/hip_bf16.h>

#define BB   32
#define SS   1024
#define RR   1024
#define HID  512
#define OUTD 1024

// Layer 1 (proven round-9 form): one wave per (4-j tile, 4-batch tile).
// Grid: 128 j-quads * 8 b-quads = 1024 one-wave blocks.
__global__ __launch_bounds__(64) void layer1_kernel(
    const float* __restrict__ rep, const float* __restrict__ W1,
    const float* __restrict__ b1, float* __restrict__ h) {
  const int lane = threadIdx.x;
  const int g    = lane >> 4;
  const int l16  = lane & 15;
  const int jq   = blockIdx.x >> 3;        // 0..127
  const int b0   = (blockIdx.x & 7) << 2;  // 0,4,..,28
  const int j    = (jq << 2) + g;

  const float4* w4 = reinterpret_cast<const float4*>(W1 + (size_t)j * RR);
  const float4* r0 = reinterpret_cast<const float4*>(rep + (size_t)b0 * RR);
  const float4* r1 = reinterpret_cast<const float4*>(rep + (size_t)(b0 + 1) * RR);
  const float4* r2 = reinterpret_cast<const float4*>(rep + (size_t)(b0 + 2) * RR);
  const float4* r3 = reinterpret_cast<const float4*>(rep + (size_t)(b0 + 3) * RR);
  float a0 = 0.f, a1 = 0.f, a2 = 0.f, a3 = 0.f;
#pragma unroll
  for (int t = 0; t < 16; ++t) {           // 256 float4 / 16 lanes
    const int idx = l16 + 16 * t;
    const float4 w = w4[idx];
    const float4 x0 = r0[idx];
    const float4 x1 = r1[idx];
    const float4 x2 = r2[idx];
    const float4 x3 = r3[idx];
    a0 += w.x * x0.x + w.y * x0.y + w.z * x0.z + w.w * x0.w;
    a1 += w.x * x1.x + w.y * x1.y + w.z * x1.z + w.w * x1.w;
    a2 += w.x * x2.x + w.y * x2.y + w.z * x2.z + w.w * x2.w;
    a3 += w.x * x3.x + w.y * x3.y + w.z * x3.z + w.w * x3.w;
  }
#pragma unroll
  for (int m = 1; m <= 8; m <<= 1) {
    a0 += __shfl_xor(a0, m);
    a1 += __shfl_xor(a1, m);
    a2 += __shfl_xor(a2, m);
    a3 += __shfl_xor(a3, m);
  }
  if (l16 == 0) {
    const float bb = b1[j];
    h[(size_t)b0 * HID + j]       = fmaxf(a0 + bb, 0.f);
    h[(size_t)(b0 + 1) * HID + j] = fmaxf(a1 + bb, 0.f);
    h[(size_t)(b0 + 2) * HID + j] = fmaxf(a2 + bb, 0.f);
    h[(size_t)(b0 + 3) * HID + j] = fmaxf(a3 + bb, 0.f);
  }
}

// Fused layer2 + broadcast, REDUNDANCY-1 variant.
// Block = (b, k-chunk of 64), covering ALL 1024 s-rows. Grid = 32*16 = 512.
// W2 is read exactly once per batch: 64 MB L2 total = 256 KB/CU bubble.
// Dot phase: 16 groups x 4 k's (32 serial MACs/thread, h staged in LDS).
// Write phase: 1024 rows x 256 B contiguous chunks, 64 stores/thread.
__global__ __launch_bounds__(256) void l2bcast_kernel(
    const float* __restrict__ h, const float* __restrict__ W2,
    const float* __restrict__ b2, float* __restrict__ out) {
  __shared__ float s_h[HID];      // 2 KB
  __shared__ float s_o[64];       // 256 B
  const int tid = threadIdx.x;
  const int b   = blockIdx.x >> 4;         // 0..31
  const int kc  = blockIdx.x & 15;         // 0..15
  const int k0  = kc << 6;                 // 64 k's per block

  // stage h[b,:] (512 floats, one float2 per thread)
  reinterpret_cast<float2*>(s_h)[tid] =
      reinterpret_cast<const float2*>(h + (size_t)b * HID)[tid];
  __syncthreads();

  const int gg  = tid >> 4;      // 0..15
  const int l16 = tid & 15;
  const float4* s_h4 = reinterpret_cast<const float4*>(s_h);
#pragma unroll
  for (int i = 0; i < 4; ++i) {
    const int k = k0 + (i << 4) + gg;
    const float4* w = reinterpret_cast<const float4*>(W2 + (size_t)k * HID);
    float acc = 0.f;
#pragma unroll
    for (int t = 0; t < 8; ++t) {          // 128 float4 / 16 lanes
      const float4 wv = w[l16 + 16 * t];
      const float4 xv = s_h4[l16 + 16 * t];
      acc += wv.x * xv.x + wv.y * xv.y + wv.z * xv.z + wv.w * xv.w;
    }
#pragma unroll
    for (int m = 1; m <= 8; m <<= 1) acc += __shfl_xor(acc, m);
    if (l16 == 0) s_o[(i << 4) + gg] = acc + b2[k];
  }
  __syncthreads();

  // write phase: all 1024 rows; 16 rows per pass, 64 passes.
  // thread -> (row r0 = tid>>4, float4 col = tid&15): 256 B per row chunk.
  const float4 v = reinterpret_cast<const float4*>(s_o)[tid & 15];
  const int r0 = tid >> 4;                 // 0..15
  float4* __restrict__ o4 =
      reinterpret_cast<float4*>(out) + (size_t)b * SS * (OUTD / 4) + (k0 >> 2);
#pragma unroll
  for (int p = 0; p < 64; ++p) {
    const int s = r0 + (p << 4);
    o4[(size_t)s * (OUTD / 4) + (tid & 15)] = v;
  }
}

extern "C" void kernel_launch(void* const* d_in, const int* in_sizes, int n_in,
                              void* d_out, int out_size, void* d_ws, size_t ws_size,
                              hipStream_t stream) {
  const float* rep = (const float*)d_in[0];
  // d_in[1] = size_matrix: only its shape matters (ones_like) -> unused
  const float* W1 = (const float*)d_in[2];
  const float* b1 = (const float*)d_in[3];
  const float* W2 = (const float*)d_in[4];
  const float* b2 = (const float*)d_in[5];
  float* out = (float*)d_out;
  float* h   = (float*)d_ws;               // 32*512 floats = 64 KB

  layer1_kernel<<<1024, 64, 0, stream>>>(rep, W1, b1, h);
  l2bcast_kernel<<<512, 256, 0, stream>>>(h, W2, b2, out);
}